// Round 9
// baseline (482.321 us; speedup 1.0000x reference)
//
#include <hip/hip_runtime.h>

using bf16x8 = __attribute__((ext_vector_type(8))) __bf16;
using f32x4  = __attribute__((ext_vector_type(4))) float;
using uint2v = __attribute__((ext_vector_type(2))) unsigned int;

__device__ __forceinline__ unsigned short f2bf(float x) {
  unsigned int u = __float_as_uint(x);
  u += 0x7fffu + ((u >> 16) & 1u);   // RNE
  return (unsigned short)(u >> 16);
}

__device__ __forceinline__ void gload16(const unsigned short* g, unsigned short* l) {
  __builtin_amdgcn_global_load_lds(
      (__attribute__((address_space(1))) void*)const_cast<unsigned short*>(g),
      (__attribute__((address_space(3))) void*)l, 16, 0, 0);
}

// ---------------- fp32 -> bf16 convert ----------------
__global__ __launch_bounds__(256) void cvt_kernel(const float* __restrict__ in,
                                                  unsigned short* __restrict__ out) {
  const int i = blockIdx.x * 256 + threadIdx.x;
  const float4 v = ((const float4*)in)[i];
  ushort4 o;
  o.x = f2bf(v.x); o.y = f2bf(v.y); o.z = f2bf(v.z); o.w = f2bf(v.w);
  ((ushort4*)out)[i] = o;
}

// ---------------- NT GEMM, 256x256 tile, BK=64, quadrant-phased (4 phases/K-tile) ------
// C[M,N] = A[M,K] * B[N,K]^T, bf16 in, fp32 acc. 512 threads = 8 waves (2M x 4N),
// per-wave 128x64 output. LDS 2 bufs x (A[256][64] + B[256][64]) = 128 KB, chunk^=(row&7)
// swizzle via pre-swizzled global source. Per phase: ds-read new frags + 2 staging
// gload_lds -> barrier -> lgkmcnt(0) -> setprio(1) 16 MFMA setprio(0) -> barrier.
// Tile boundary: per-wave vmcnt(0) then barrier => next tile's buffer fully landed. Race-free.
// MODE 0: scatter to QKV buffer; Q,K as [bh][s][d]; V TRANSPOSED as [bh][d][s]
// MODE 1: fp32 row-major to Cf
#define LOADA(mh) { _Pragma("unroll") for (int mf = 0; mf < 4; ++mf) { \
    const int row_ = wm * 128 + (mh) * 64 + mf * 16 + lrow; \
    af[mf][0] = *(const bf16x8*)(cb + row_ * 64 + ((lhi ^ (lrow & 7)) << 3)); \
    af[mf][1] = *(const bf16x8*)(cb + row_ * 64 + (((lhi + 4) ^ (lrow & 7)) << 3)); } }
#define LOADB(nh) { _Pragma("unroll") for (int nf = 0; nf < 2; ++nf) { \
    const int row_ = wn * 64 + (nh) * 32 + nf * 16 + lrow; \
    bfr[nf][0] = *(const bf16x8*)(cb + 16384 + row_ * 64 + ((lhi ^ (lrow & 7)) << 3)); \
    bfr[nf][1] = *(const bf16x8*)(cb + 16384 + row_ * 64 + (((lhi + 4) ^ (lrow & 7)) << 3)); } }
#define MMAQ(mh, nh) { \
    __builtin_amdgcn_s_setprio(1); \
    _Pragma("unroll") for (int mf = 0; mf < 4; ++mf) \
      _Pragma("unroll") for (int nf = 0; nf < 2; ++nf) \
        _Pragma("unroll") for (int ks = 0; ks < 2; ++ks) \
          acc[(mh) * 4 + mf][(nh) * 2 + nf] = __builtin_amdgcn_mfma_f32_16x16x32_bf16( \
              af[mf][ks], bfr[nf][ks], acc[(mh) * 4 + mf][(nh) * 2 + nf], 0, 0, 0); \
    __builtin_amdgcn_s_setprio(0); }
#define PHASE_SYNC_PRE() { __builtin_amdgcn_s_barrier(); \
    asm volatile("s_waitcnt lgkmcnt(0)" ::: "memory"); \
    __builtin_amdgcn_sched_barrier(0); }

template<int MODE>
__global__ __launch_bounds__(512, 2)
void gemm256(const unsigned short* __restrict__ A,
             const unsigned short* __restrict__ Bw,
             float* __restrict__ Cf,
             unsigned short* __restrict__ Cq,
             int M, int N, int K)
{
  __shared__ unsigned short Sh[2][32768];   // per buf: A at 0, B at 16384 (ushorts)
  const int tid  = threadIdx.x;
  const int lane = tid & 63;
  const int wid  = tid >> 6;
  const int wm   = wid >> 2;      // 0..1
  const int wn   = wid & 3;       // 0..3
  const int lrow = lane & 15, lhi = lane >> 4;

  // XCD-aware bijective swizzle (nwg % 8 == 0 for both grids)
  const int gY   = gridDim.y;
  const int nwg  = gridDim.x * gY;
  const int flat = blockIdx.x * gY + blockIdx.y;
  const int swzb = (flat & 7) * (nwg >> 3) + (flat >> 3);
  const int bn   = (swzb / gY) * 256;
  const int bm   = (swzb % gY) * 256;
  const int NT   = K >> 6;

  // staging: thread covers 16B: row = tid>>3 (0..63), chunk = tid&7; source pre-XOR'd
  const int srow = tid >> 3;
  const int sswz = ((tid & 7) ^ (srow & 7)) << 3;
  const unsigned short* AgS = A  + (size_t)(bm + srow) * K + sswz;
  const unsigned short* BgS = Bw + (size_t)(bn + srow) * K + sswz;

  f32x4  acc[8][4] = {};
  bf16x8 af[4][2], bfr[2][2];

  // ---- prologue: stage tile 0 fully, drain
  gload16(AgS,                   &Sh[0][0] + tid * 8);
  gload16(AgS + (size_t)64  * K, &Sh[0][0] + 4096  + tid * 8);
  gload16(AgS + (size_t)128 * K, &Sh[0][0] + 8192  + tid * 8);
  gload16(AgS + (size_t)192 * K, &Sh[0][0] + 12288 + tid * 8);
  gload16(BgS,                   &Sh[0][0] + 16384 + tid * 8);
  gload16(BgS + (size_t)64  * K, &Sh[0][0] + 20480 + tid * 8);
  gload16(BgS + (size_t)128 * K, &Sh[0][0] + 24576 + tid * 8);
  gload16(BgS + (size_t)192 * K, &Sh[0][0] + 28672 + tid * 8);
  asm volatile("s_waitcnt vmcnt(0)" ::: "memory");
  __builtin_amdgcn_s_barrier();

  for (int t = 0; t < NT; ++t) {
    const unsigned short* cb = &Sh[t & 1][0];
    unsigned short* nb = &Sh[(t + 1) & 1][0];
    const unsigned short* agn = AgS + (size_t)(t + 1) * 64;
    const unsigned short* bgn = BgS + (size_t)(t + 1) * 64;
    const bool pre = (t + 1 < NT);

    // phase 1: Q(0,0); read A(0)+B(0); stage next A rows 0-127
    LOADA(0); LOADB(0);
    if (pre) { gload16(agn, nb + tid * 8); gload16(agn + (size_t)64 * K, nb + 4096 + tid * 8); }
    PHASE_SYNC_PRE();
    MMAQ(0, 0);
    __builtin_amdgcn_s_barrier();

    // phase 2: Q(0,1); read B(1); stage next A rows 128-255
    LOADB(1);
    if (pre) { gload16(agn + (size_t)128 * K, nb + 8192 + tid * 8);
               gload16(agn + (size_t)192 * K, nb + 12288 + tid * 8); }
    PHASE_SYNC_PRE();
    MMAQ(0, 1);
    __builtin_amdgcn_s_barrier();

    // phase 3: Q(1,1); read A(1); stage next B rows 0-127
    LOADA(1);
    if (pre) { gload16(bgn, nb + 16384 + tid * 8);
               gload16(bgn + (size_t)64 * K, nb + 20480 + tid * 8); }
    PHASE_SYNC_PRE();
    MMAQ(1, 1);
    __builtin_amdgcn_s_barrier();

    // phase 4: Q(1,0); read B(0) again; stage next B rows 128-255
    LOADB(0);
    if (pre) { gload16(bgn + (size_t)128 * K, nb + 24576 + tid * 8);
               gload16(bgn + (size_t)192 * K, nb + 28672 + tid * 8); }
    PHASE_SYNC_PRE();
    MMAQ(1, 0);
    asm volatile("s_waitcnt vmcnt(0)" ::: "memory");   // per-wave drain; barrier makes it global
    __builtin_amdgcn_s_barrier();
  }

  // ---- epilogue: C/D layout col=lane&15 (N), row=(lane>>4)*4+r (M)
#pragma unroll
  for (int ai = 0; ai < 8; ++ai) {
    const int row0 = bm + wm * 128 + (ai >> 2) * 64 + (ai & 3) * 16 + lhi * 4;
#pragma unroll
    for (int bj = 0; bj < 4; ++bj) {
      const int col = bn + wn * 64 + (bj >> 1) * 32 + (bj & 1) * 16 + lrow;
#pragma unroll
      for (int r = 0; r < 4; ++r) {
        const int row = row0 + r;
        const float v = acc[ai][bj][r];
        if (MODE == 0) {
          const int which = col >> 11;
          const int h = (col >> 6) & 31;
          const int d = col & 63;
          const int b = row >> 11;
          const int s = row & 2047;
          if (which == 2) {
            Cq[(size_t)16777216 + ((size_t)(b * 32 + h) * 64 + d) * 2048 + s] = f2bf(v);
          } else {
            Cq[(((size_t)which * 64 + b * 32 + h) * 2048 + s) * 64 + d] = f2bf(v);
          }
        } else {
          Cf[(size_t)row * N + col] = v;
        }
      }
    }
  }
}

// ---------------- flash attention, fixed-shift softmax + ones-MFMA row-sum ----------------
__global__ __launch_bounds__(256)
void attn_kernel(const unsigned short* __restrict__ QKV,
                 const float* __restrict__ mask,
                 unsigned short* __restrict__ Ctx)
{
  constexpr int S = 2048, D = 64, BH = 64;
  __shared__ unsigned short Klds[2][64 * 64];
  __shared__ unsigned short Vlds[2][64 * 64];
  __shared__ unsigned short PT[4][64 * 16];

  const int tid  = threadIdx.x;
  const int lane = tid & 63;
  const int wid  = tid >> 6;
  const int lrow = lane & 15;
  const int lhi  = lane >> 4;
  const int bh = blockIdx.y;
  const int b  = bh >> 5;
  const int h  = bh & 31;
  const int qbase = blockIdx.x * 64;

  const size_t qoff = (size_t)bh * S * D;
  const size_t koff = qoff + (size_t)BH * S * D;
  const size_t voff = koff + (size_t)BH * S * D;   // V^T region: [d][s]

  bf16x8 qa0, qa1;
  {
    const unsigned short* Qp = QKV + qoff + (size_t)(qbase + wid * 16 + lrow) * D + lhi * 8;
    qa0 = *(const bf16x8*)Qp;
    qa1 = *(const bf16x8*)(Qp + 32);
  }

  bf16x8 vones;
#pragma unroll
  for (int j = 0; j < 8; ++j) vones[j] = (__bf16)1.0f;

  f32x4 oacc[4] = {};
  f32x4 osum = {};    // row-sum via ones-MFMA; same (lhi*4+r) row mapping as oacc

  const int strow  = tid >> 3;
  const int sswz   = ((tid & 7) ^ (strow & 7)) << 3;
  const unsigned short* Kg = QKV + koff + (size_t)strow * D + sswz;
  const unsigned short* Vg = QKV + voff + (size_t)strow * S + sswz;

  const float k1 = 0.125f * 1.44269504f;  // (1/sqrt(64)) * log2(e)
  const unsigned ptbase =
      (unsigned)(uintptr_t)&PT[wid][0] + (unsigned)(lane * 8 + (lane >> 4) * 128);

  auto stage = [&](int t, int c) {
    const int kb = t * 64;
    gload16(Kg + (size_t)kb * D,          &Klds[c][0] + tid * 8);
    gload16(Kg + (size_t)kb * D + 32 * D, &Klds[c][0] + 2048 + tid * 8);
    gload16(Vg + kb,                      &Vlds[c][0] + tid * 8);
    gload16(Vg + kb + 32 * S,             &Vlds[c][0] + 2048 + tid * 8);
  };

  stage(0, 0);
  __syncthreads();

  for (int t = 0; t < S / 64; ++t) {
    const int kb  = t * 64;
    const int cur = t & 1;
    if (t + 1 < S / 64) stage(t + 1, cur ^ 1);

    float mkl[4];
#pragma unroll
    for (int f = 0; f < 4; ++f)
      mkl[f] = mask[(size_t)b * S + kb + lrow + 16 * f] * 1.44269504f;

    const unsigned short* Kc = &Klds[cur][0];
    f32x4 sacc[4] = {};
    __builtin_amdgcn_s_setprio(1);
#pragma unroll
    for (int f = 0; f < 4; ++f) {
      const int krw = f * 16 + lrow;
      bf16x8 kf0 = *(const bf16x8*)(Kc + krw * 64 + ((lhi ^ (lrow & 7)) << 3));
      bf16x8 kf1 = *(const bf16x8*)(Kc + krw * 64 + (((lhi + 4) ^ (lrow & 7)) << 3));
      sacc[f] = __builtin_amdgcn_mfma_f32_16x16x32_bf16(qa0, kf0, sacc[f], 0, 0, 0);
      sacc[f] = __builtin_amdgcn_mfma_f32_16x16x32_bf16(qa1, kf1, sacc[f], 0, 0, 0);
    }
    __builtin_amdgcn_s_setprio(0);

    // fixed-shift softmax: p = exp2(s*k1 + mask); row-sum deferred to ones-MFMA
#pragma unroll
    for (int f = 0; f < 4; ++f)
#pragma unroll
      for (int r = 0; r < 4; ++r)
        sacc[f][r] = __builtin_amdgcn_exp2f(sacc[f][r] * k1 + mkl[f]);

    // P^T pack into PT[k][q] ([64][16] row-major), packed b64 writes
    unsigned short* PTw = &PT[wid][0];
#pragma unroll
    for (int f = 0; f < 4; ++f) {
      unsigned w0, w1;
      asm("v_cvt_pk_bf16_f32 %0, %1, %2" : "=v"(w0) : "v"(sacc[f][0]), "v"(sacc[f][1]));
      asm("v_cvt_pk_bf16_f32 %0, %1, %2" : "=v"(w1) : "v"(sacc[f][2]), "v"(sacc[f][3]));
      uint2v w; w.x = w0; w.y = w1;
      *(uint2v*)(PTw + (lrow + 16 * f) * 16 + lhi * 4) = w;
    }

    // PV: O += P[16x64] * V[64x64]; osum += P * ones
    const unsigned short* Vc = &Vlds[cur][0];
    uint2v r0, r1, r2, r3;
    asm volatile("ds_read_b64_tr_b16 %0, %1"             : "=v"(r0) : "v"(ptbase) : "memory");
    asm volatile("ds_read_b64_tr_b16 %0, %1 offset:128"  : "=v"(r1) : "v"(ptbase) : "memory");
    asm volatile("ds_read_b64_tr_b16 %0, %1 offset:1024" : "=v"(r2) : "v"(ptbase) : "memory");
    asm volatile("ds_read_b64_tr_b16 %0, %1 offset:1152" : "=v"(r3) : "v"(ptbase) : "memory");
    bf16x8 vb[2][4];
#pragma unroll
    for (int ks = 0; ks < 2; ++ks)
#pragma unroll
      for (int f = 0; f < 4; ++f) {
        const int dc = lrow + 16 * f;
        vb[ks][f] = *(const bf16x8*)(Vc + dc * 64 + (((ks * 4 + lhi) ^ (dc & 7)) << 3));
      }
    asm volatile("s_waitcnt lgkmcnt(0)" ::: "memory");
    __builtin_amdgcn_sched_barrier(0);
    union { struct { uint2v a, b; } u; bf16x8 v; } p0, p1;
    p0.u.a = r0; p0.u.b = r1;
    p1.u.a = r2; p1.u.b = r3;
    __builtin_amdgcn_s_setprio(1);
#pragma unroll
    for (int f = 0; f < 4; ++f)
      oacc[f] = __builtin_amdgcn_mfma_f32_16x16x32_bf16(p0.v, vb[0][f], oacc[f], 0, 0, 0);
    osum = __builtin_amdgcn_mfma_f32_16x16x32_bf16(p0.v, vones, osum, 0, 0, 0);
#pragma unroll
    for (int f = 0; f < 4; ++f)
      oacc[f] = __builtin_amdgcn_mfma_f32_16x16x32_bf16(p1.v, vb[1][f], oacc[f], 0, 0, 0);
    osum = __builtin_amdgcn_mfma_f32_16x16x32_bf16(p1.v, vones, osum, 0, 0, 0);
    __builtin_amdgcn_s_setprio(0);
    __syncthreads();
  }

  // write ctx [B,S,HID] bf16, fusing [B,H,S,D] -> [B,S,H*D]
#pragma unroll
  for (int f = 0; f < 4; ++f) {
    const int d = lrow + 16 * f;
#pragma unroll
    for (int r = 0; r < 4; ++r) {
      const int q = qbase + wid * 16 + lhi * 4 + r;
      const float v = oacc[f][r] / osum[r];
      Ctx[((size_t)b * S + q) * 2048 + h * 64 + d] = f2bf(v);
    }
  }
}

// ---------------- launch ----------------
extern "C" void kernel_launch(void* const* d_in, const int* in_sizes, int n_in,
                              void* d_out, int out_size, void* d_ws, size_t ws_size,
                              hipStream_t stream) {
  const float* X    = (const float*)d_in[0];
  const float* mask = (const float*)d_in[1];
  const float* wq   = (const float*)d_in[2];
  const float* wk   = (const float*)d_in[3];
  const float* wv   = (const float*)d_in[4];
  const float* wo   = (const float*)d_in[5];

  unsigned short* ws   = (unsigned short*)d_ws;
  unsigned short* Xb   = ws;                    //  8,388,608  X bf16 [4096][2048]
  unsigned short* Wcat = Xb + 8388608;          // 12,582,912  [Wq;Wk;Wv] bf16 [6144][2048]
  unsigned short* Wob  = Wcat + 12582912;       //  4,194,304  Wo bf16 [2048][2048]
  unsigned short* QKVb = Wob + 4194304;         // 25,165,824  Q,K: [bh][s][d]; V: [bh][d][s]
  unsigned short* Ctxb = QKVb + 25165824;       //  8,388,608  ctx bf16 [4096][2048]

  cvt_kernel<<<8192, 256, 0, stream>>>(X, Xb);
  cvt_kernel<<<4096, 256, 0, stream>>>(wq, Wcat);
  cvt_kernel<<<4096, 256, 0, stream>>>(wk, Wcat + 4194304);
  cvt_kernel<<<4096, 256, 0, stream>>>(wv, Wcat + 8388608);
  cvt_kernel<<<4096, 256, 0, stream>>>(wo, Wob);

  // QKV projection: [4096x2048] x [6144x2048]^T; grid 24x16 = 384 blocks (%8==0)
  gemm256<0><<<dim3(24, 16), 512, 0, stream>>>(Xb, Wcat, nullptr, QKVb, 4096, 6144, 2048);

  // flash attention over 64 (b,h) pairs x 32 q-tiles
  attn_kernel<<<dim3(32, 64), 256, 0, stream>>>(QKVb, mask, Ctxb);

  // output projection: [4096x2048] x [2048x2048]^T -> fp32; grid 8x16 = 128 blocks
  gemm256<1><<<dim3(8, 16), 512, 0, stream>>>(Ctxb, Wob, (float*)d_out, nullptr, 4096, 2048, 2048);
}

// Round 10
// 458.903 us; speedup vs baseline: 1.0510x; 1.0510x over previous
//
#include <hip/hip_runtime.h>

using bf16x8 = __attribute__((ext_vector_type(8))) __bf16;
using f32x4  = __attribute__((ext_vector_type(4))) float;
using uint2v = __attribute__((ext_vector_type(2))) unsigned int;

__device__ __forceinline__ unsigned short f2bf(float x) {
  unsigned int u = __float_as_uint(x);
  u += 0x7fffu + ((u >> 16) & 1u);   // RNE
  return (unsigned short)(u >> 16);
}

__device__ __forceinline__ void gload16(const unsigned short* g, unsigned short* l) {
  __builtin_amdgcn_global_load_lds(
      (__attribute__((address_space(1))) void*)const_cast<unsigned short*>(g),
      (__attribute__((address_space(3))) void*)l, 16, 0, 0);
}

// ---------------- fp32 -> bf16 convert ----------------
__global__ __launch_bounds__(256) void cvt_kernel(const float* __restrict__ in,
                                                  unsigned short* __restrict__ out) {
  const int i = blockIdx.x * 256 + threadIdx.x;
  const float4 v = ((const float4*)in)[i];
  ushort4 o;
  o.x = f2bf(v.x); o.y = f2bf(v.y); o.z = f2bf(v.z); o.w = f2bf(v.w);
  ((ushort4*)out)[i] = o;
}

// ---------------- NT GEMM, 128x128 tile, BK=32, double-buf counted-vmcnt, 4 waves ------
// C[M,N] = A[M,K] * B[N,K]^T, bf16 in, fp32 acc. 256 threads = 4 waves (2x2),
// per-wave 64x64 (4x4 frags of 16x16x32). LDS: 2 bufs x (A[128][32]+B[128][32]) = 32 KB
// -> up to 5 blocks/CU (20 waves): cross-block overlap hides barriers/drains (m97/m114).
// Swizzle: 16B-chunk ^= (row>>1)&3 (2-way banks = free), via pre-swizzled global source.
// Per K-step: issue stage(t+1) -> vmcnt(4) (t landed, t+1 in flight) -> BAR -> compute(t)
// -> BAR. Counted vmcnt, never 0 mid-loop. Exact grids: G1 1536 = 6x256, G2 512 = 2x256.
// MODE 0: scatter Q,K as [bh][s][d], V transposed as [bh][d][s]. MODE 1: fp32 row-major.
template<int MODE>
__global__ __launch_bounds__(256, 4)
void gemm128(const unsigned short* __restrict__ A,
             const unsigned short* __restrict__ Bw,
             float* __restrict__ Cf,
             unsigned short* __restrict__ Cq,
             int M, int N, int K)
{
  __shared__ unsigned short Sh[2][8192];   // per buf: A at 0, B at 4096 (ushorts)
  const int tid  = threadIdx.x;
  const int lane = tid & 63;
  const int wid  = tid >> 6;
  const int wr   = wid >> 1, wc = wid & 1;
  const int lrow = lane & 15, lhi = lane >> 4;

  // XCD-aware bijective swizzle (nwg % 8 == 0: 1536 / 512)
  const int gY   = gridDim.y;
  const int nwg  = gridDim.x * gY;
  const int flat = blockIdx.x * gY + blockIdx.y;
  const int swzb = (flat & 7) * (nwg >> 3) + (flat >> 3);
  const int bn   = (swzb / gY) * 128;
  const int bm   = (swzb % gY) * 128;
  const int NT   = K >> 5;

  // staging: thread covers 16B: row = tid>>2 (0..63), chunk = tid&3; source chunk
  // pre-XOR'd with (row>>1)&3 so linear LDS dest == swizzled layout (rule #21)
  const int srow = tid >> 2;
  const int sswz = ((tid & 3) ^ ((tid >> 3) & 3)) << 3;
  const unsigned short* AgS = A  + (size_t)(bm + srow) * K + sswz;
  const unsigned short* BgS = Bw + (size_t)(bn + srow) * K + sswz;

  // read offsets: frag row = base+lrow; (row>>1)&3 == (lrow>>1)&3 (bases are mult of 16)
  const int coff = (lhi ^ ((lrow >> 1) & 3)) << 3;
  int aoff[4], boff[4];
#pragma unroll
  for (int m = 0; m < 4; ++m) aoff[m] = (wr * 64 + m * 16 + lrow) * 32 + coff;
#pragma unroll
  for (int n = 0; n < 4; ++n) boff[n] = 4096 + (wc * 64 + n * 16 + lrow) * 32 + coff;

  f32x4 acc[4][4] = {};

  auto stage = [&](int t, unsigned short* buf) {
    const unsigned short* ag = AgS + (size_t)t * 32;
    const unsigned short* bg = BgS + (size_t)t * 32;
    gload16(ag,                  buf + tid * 8);           // A rows 0-63
    gload16(ag + (size_t)64 * K, buf + 2048 + tid * 8);    // A rows 64-127
    gload16(bg,                  buf + 4096 + tid * 8);    // B rows 0-63
    gload16(bg + (size_t)64 * K, buf + 6144 + tid * 8);    // B rows 64-127
  };

  stage(0, &Sh[0][0]);

  for (int t = 0; t < NT; ++t) {
    if (t + 1 < NT) {
      stage(t + 1, &Sh[(t + 1) & 1][0]);
      asm volatile("s_waitcnt vmcnt(4)" ::: "memory");   // stage(t) landed; t+1 in flight
    } else {
      asm volatile("s_waitcnt vmcnt(0)" ::: "memory");   // last tile: drain
    }
    __builtin_amdgcn_s_barrier();                        // all waves' stage(t) landed
    asm volatile("" ::: "memory");                       // pin ds_reads below the barrier

    const unsigned short* cb = &Sh[t & 1][0];
    bf16x8 af[4], bfr[4];
#pragma unroll
    for (int m = 0; m < 4; ++m) af[m]  = *(const bf16x8*)(cb + aoff[m]);
#pragma unroll
    for (int n = 0; n < 4; ++n) bfr[n] = *(const bf16x8*)(cb + boff[n]);
    __builtin_amdgcn_s_setprio(1);
#pragma unroll
    for (int m = 0; m < 4; ++m)
#pragma unroll
      for (int n = 0; n < 4; ++n)
        acc[m][n] = __builtin_amdgcn_mfma_f32_16x16x32_bf16(af[m], bfr[n], acc[m][n], 0, 0, 0);
    __builtin_amdgcn_s_setprio(0);
    __builtin_amdgcn_s_barrier();                        // reads(t) done before buf reuse
  }

  // ---- epilogue: C/D layout col=lane&15 (N), row=(lane>>4)*4+r (M)
#pragma unroll
  for (int m = 0; m < 4; ++m) {
    const int row0 = bm + wr * 64 + m * 16 + lhi * 4;
#pragma unroll
    for (int n = 0; n < 4; ++n) {
      const int col = bn + wc * 64 + n * 16 + lrow;
#pragma unroll
      for (int r = 0; r < 4; ++r) {
        const int row = row0 + r;
        const float v = acc[m][n][r];
        if (MODE == 0) {
          const int which = col >> 11;
          const int h = (col >> 6) & 31;
          const int d = col & 63;
          const int b = row >> 11;
          const int s = row & 2047;
          if (which == 2) {
            // V transposed: region + [b*32+h][d][s]
            Cq[(size_t)16777216 + ((size_t)(b * 32 + h) * 64 + d) * 2048 + s] = f2bf(v);
          } else {
            Cq[(((size_t)which * 64 + b * 32 + h) * 2048 + s) * 64 + d] = f2bf(v);
          }
        } else {
          Cf[(size_t)row * N + col] = v;
        }
      }
    }
  }
}

// ---------------- flash attention, fixed-shift softmax + ones-MFMA row-sum ----------------
__global__ __launch_bounds__(256)
void attn_kernel(const unsigned short* __restrict__ QKV,
                 const float* __restrict__ mask,
                 unsigned short* __restrict__ Ctx)
{
  constexpr int S = 2048, D = 64, BH = 64;
  __shared__ unsigned short Klds[2][64 * 64];
  __shared__ unsigned short Vlds[2][64 * 64];
  __shared__ unsigned short PT[4][64 * 16];

  const int tid  = threadIdx.x;
  const int lane = tid & 63;
  const int wid  = tid >> 6;
  const int lrow = lane & 15;
  const int lhi  = lane >> 4;
  const int bh = blockIdx.y;
  const int b  = bh >> 5;
  const int h  = bh & 31;
  const int qbase = blockIdx.x * 64;

  const size_t qoff = (size_t)bh * S * D;
  const size_t koff = qoff + (size_t)BH * S * D;
  const size_t voff = koff + (size_t)BH * S * D;   // V^T region: [d][s]

  bf16x8 qa0, qa1;
  {
    const unsigned short* Qp = QKV + qoff + (size_t)(qbase + wid * 16 + lrow) * D + lhi * 8;
    qa0 = *(const bf16x8*)Qp;
    qa1 = *(const bf16x8*)(Qp + 32);
  }

  bf16x8 vones;
#pragma unroll
  for (int j = 0; j < 8; ++j) vones[j] = (__bf16)1.0f;

  f32x4 oacc[4] = {};
  f32x4 osum = {};    // row-sum via ones-MFMA; same (lhi*4+r) row mapping as oacc

  const int strow  = tid >> 3;
  const int sswz   = ((tid & 7) ^ (strow & 7)) << 3;
  const unsigned short* Kg = QKV + koff + (size_t)strow * D + sswz;
  const unsigned short* Vg = QKV + voff + (size_t)strow * S + sswz;

  const float k1 = 0.125f * 1.44269504f;  // (1/sqrt(64)) * log2(e)
  const unsigned ptbase =
      (unsigned)(uintptr_t)&PT[wid][0] + (unsigned)(lane * 8 + (lane >> 4) * 128);

  auto stage = [&](int t, int c) {
    const int kb = t * 64;
    gload16(Kg + (size_t)kb * D,          &Klds[c][0] + tid * 8);
    gload16(Kg + (size_t)kb * D + 32 * D, &Klds[c][0] + 2048 + tid * 8);
    gload16(Vg + kb,                      &Vlds[c][0] + tid * 8);
    gload16(Vg + kb + 32 * S,             &Vlds[c][0] + 2048 + tid * 8);
  };

  stage(0, 0);
  __syncthreads();

  for (int t = 0; t < S / 64; ++t) {
    const int kb  = t * 64;
    const int cur = t & 1;
    if (t + 1 < S / 64) stage(t + 1, cur ^ 1);

    float mkl[4];
#pragma unroll
    for (int f = 0; f < 4; ++f)
      mkl[f] = mask[(size_t)b * S + kb + lrow + 16 * f] * 1.44269504f;

    const unsigned short* Kc = &Klds[cur][0];
    f32x4 sacc[4] = {};
    __builtin_amdgcn_s_setprio(1);
#pragma unroll
    for (int f = 0; f < 4; ++f) {
      const int krw = f * 16 + lrow;
      bf16x8 kf0 = *(const bf16x8*)(Kc + krw * 64 + ((lhi ^ (lrow & 7)) << 3));
      bf16x8 kf1 = *(const bf16x8*)(Kc + krw * 64 + (((lhi + 4) ^ (lrow & 7)) << 3));
      sacc[f] = __builtin_amdgcn_mfma_f32_16x16x32_bf16(qa0, kf0, sacc[f], 0, 0, 0);
      sacc[f] = __builtin_amdgcn_mfma_f32_16x16x32_bf16(qa1, kf1, sacc[f], 0, 0, 0);
    }
    __builtin_amdgcn_s_setprio(0);

    // fixed-shift softmax: p = exp2(s*k1 + mask); row-sum deferred to ones-MFMA
#pragma unroll
    for (int f = 0; f < 4; ++f)
#pragma unroll
      for (int r = 0; r < 4; ++r)
        sacc[f][r] = __builtin_amdgcn_exp2f(sacc[f][r] * k1 + mkl[f]);

    // P^T pack into PT[k][q] ([64][16] row-major), packed b64 writes
    unsigned short* PTw = &PT[wid][0];
#pragma unroll
    for (int f = 0; f < 4; ++f) {
      unsigned w0, w1;
      asm("v_cvt_pk_bf16_f32 %0, %1, %2" : "=v"(w0) : "v"(sacc[f][0]), "v"(sacc[f][1]));
      asm("v_cvt_pk_bf16_f32 %0, %1, %2" : "=v"(w1) : "v"(sacc[f][2]), "v"(sacc[f][3]));
      uint2v w; w.x = w0; w.y = w1;
      *(uint2v*)(PTw + (lrow + 16 * f) * 16 + lhi * 4) = w;
    }

    // PV: O += P[16x64] * V[64x64]; osum += P * ones
    const unsigned short* Vc = &Vlds[cur][0];
    uint2v r0, r1, r2, r3;
    asm volatile("ds_read_b64_tr_b16 %0, %1"             : "=v"(r0) : "v"(ptbase) : "memory");
    asm volatile("ds_read_b64_tr_b16 %0, %1 offset:128"  : "=v"(r1) : "v"(ptbase) : "memory");
    asm volatile("ds_read_b64_tr_b16 %0, %1 offset:1024" : "=v"(r2) : "v"(ptbase) : "memory");
    asm volatile("ds_read_b64_tr_b16 %0, %1 offset:1152" : "=v"(r3) : "v"(ptbase) : "memory");
    bf16x8 vb[2][4];
#pragma unroll
    for (int ks = 0; ks < 2; ++ks)
#pragma unroll
      for (int f = 0; f < 4; ++f) {
        const int dc = lrow + 16 * f;
        vb[ks][f] = *(const bf16x8*)(Vc + dc * 64 + (((ks * 4 + lhi) ^ (dc & 7)) << 3));
      }
    asm volatile("s_waitcnt lgkmcnt(0)" ::: "memory");
    __builtin_amdgcn_sched_barrier(0);
    union { struct { uint2v a, b; } u; bf16x8 v; } p0, p1;
    p0.u.a = r0; p0.u.b = r1;
    p1.u.a = r2; p1.u.b = r3;
    __builtin_amdgcn_s_setprio(1);
#pragma unroll
    for (int f = 0; f < 4; ++f)
      oacc[f] = __builtin_amdgcn_mfma_f32_16x16x32_bf16(p0.v, vb[0][f], oacc[f], 0, 0, 0);
    osum = __builtin_amdgcn_mfma_f32_16x16x32_bf16(p0.v, vones, osum, 0, 0, 0);
#pragma unroll
    for (int f = 0; f < 4; ++f)
      oacc[f] = __builtin_amdgcn_mfma_f32_16x16x32_bf16(p1.v, vb[1][f], oacc[f], 0, 0, 0);
    osum = __builtin_amdgcn_mfma_f32_16x16x32_bf16(p1.v, vones, osum, 0, 0, 0);
    __builtin_amdgcn_s_setprio(0);
    __syncthreads();
  }

  // write ctx [B,S,HID] bf16, fusing [B,H,S,D] -> [B,S,H*D]
#pragma unroll
  for (int f = 0; f < 4; ++f) {
    const int d = lrow + 16 * f;
#pragma unroll
    for (int r = 0; r < 4; ++r) {
      const int q = qbase + wid * 16 + lhi * 4 + r;
      const float v = oacc[f][r] / osum[r];
      Ctx[((size_t)b * S + q) * 2048 + h * 64 + d] = f2bf(v);
    }
  }
}

// ---------------- launch ----------------
extern "C" void kernel_launch(void* const* d_in, const int* in_sizes, int n_in,
                              void* d_out, int out_size, void* d_ws, size_t ws_size,
                              hipStream_t stream) {
  const float* X    = (const float*)d_in[0];
  const float* mask = (const float*)d_in[1];
  const float* wq   = (const float*)d_in[2];
  const float* wk   = (const float*)d_in[3];
  const float* wv   = (const float*)d_in[4];
  const float* wo   = (const float*)d_in[5];

  unsigned short* ws   = (unsigned short*)d_ws;
  unsigned short* Xb   = ws;                    //  8,388,608  X bf16 [4096][2048]
  unsigned short* Wcat = Xb + 8388608;          // 12,582,912  [Wq;Wk;Wv] bf16 [6144][2048]
  unsigned short* Wob  = Wcat + 12582912;       //  4,194,304  Wo bf16 [2048][2048]
  unsigned short* QKVb = Wob + 4194304;         // 25,165,824  Q,K: [bh][s][d]; V: [bh][d][s]
  unsigned short* Ctxb = QKVb + 25165824;       //  8,388,608  ctx bf16 [4096][2048]

  cvt_kernel<<<8192, 256, 0, stream>>>(X, Xb);
  cvt_kernel<<<4096, 256, 0, stream>>>(wq, Wcat);
  cvt_kernel<<<4096, 256, 0, stream>>>(wk, Wcat + 4194304);
  cvt_kernel<<<4096, 256, 0, stream>>>(wv, Wcat + 8388608);
  cvt_kernel<<<4096, 256, 0, stream>>>(wo, Wob);

  // QKV projection: grid 48x32 = 1536 = 6.0 x 256 CUs at >=1 block/CU (zero tail)
  gemm128<0><<<dim3(48, 32), 256, 0, stream>>>(Xb, Wcat, nullptr, QKVb, 4096, 6144, 2048);

  // flash attention over 64 (b,h) pairs x 32 q-tiles
  attn_kernel<<<dim3(32, 64), 256, 0, stream>>>(QKVb, mask, Ctxb);

  // output projection: grid 16x32 = 512 = 2.0 x 256 CUs (zero tail)
  gemm128<1><<<dim3(16, 32), 256, 0, stream>>>(Ctxb, Wob, (float*)d_out, nullptr, 4096, 2048, 2048);
}

// Round 11
// 448.655 us; speedup vs baseline: 1.0750x; 1.0228x over previous
//
#include <hip/hip_runtime.h>

using bf16x8 = __attribute__((ext_vector_type(8))) __bf16;
using f32x4  = __attribute__((ext_vector_type(4))) float;
using uint2v = __attribute__((ext_vector_type(2))) unsigned int;

__device__ __forceinline__ unsigned short f2bf(float x) {
  unsigned int u = __float_as_uint(x);
  u += 0x7fffu + ((u >> 16) & 1u);   // RNE
  return (unsigned short)(u >> 16);
}

__device__ __forceinline__ void gload16(const unsigned short* g, unsigned short* l) {
  __builtin_amdgcn_global_load_lds(
      (__attribute__((address_space(1))) void*)const_cast<unsigned short*>(g),
      (__attribute__((address_space(3))) void*)l, 16, 0, 0);
}

// ---------------- fp32 -> bf16 convert ----------------
__global__ __launch_bounds__(256) void cvt_kernel(const float* __restrict__ in,
                                                  unsigned short* __restrict__ out) {
  const int i = blockIdx.x * 256 + threadIdx.x;
  const float4 v = ((const float4*)in)[i];
  ushort4 o;
  o.x = f2bf(v.x); o.y = f2bf(v.y); o.z = f2bf(v.z); o.w = f2bf(v.w);
  ((ushort4*)out)[i] = o;
}

// ---------------- NT GEMM, 128x128 tile, BK=32, double-buf counted-vmcnt, 4 waves ------
// C[M,N] = A[M,K] * B[N,K]^T, bf16 in, fp32 acc. 256 threads = 4 waves (2x2),
// per-wave 64x64 (4x4 frags of 16x16x32). LDS: 2 bufs x (A[128][32]+B[128][32]) = 32 KB.
// NO XCD swizzle: round-10 A/B showed the y-fast swizzle blew HBM fetch 90->379 MB
// (L3-fit working set: default x-fastest dispatch order keeps panel sharing in L2/L3).
// Swizzle: 16B-chunk ^= (row>>1)&3 (2-way banks = free), via pre-swizzled global source.
// Per K-step: issue stage(t+1) -> vmcnt(4) (t landed, t+1 in flight) -> BAR -> compute(t)
// -> BAR. Counted vmcnt, never 0 mid-loop. Exact grids: G1 1536 = 6x256, G2 512 = 2x256.
// MODE 0: scatter Q,K as [bh][s][d], V transposed as [bh][d][s]. MODE 1: fp32 row-major.
template<int MODE>
__global__ __launch_bounds__(256, 4)
void gemm128(const unsigned short* __restrict__ A,
             const unsigned short* __restrict__ Bw,
             float* __restrict__ Cf,
             unsigned short* __restrict__ Cq,
             int M, int N, int K)
{
  __shared__ unsigned short Sh[2][8192];   // per buf: A at 0, B at 4096 (ushorts)
  const int tid  = threadIdx.x;
  const int lane = tid & 63;
  const int wid  = tid >> 6;
  const int wr   = wid >> 1, wc = wid & 1;
  const int lrow = lane & 15, lhi = lane >> 4;

  const int bn = blockIdx.x * 128;
  const int bm = blockIdx.y * 128;
  const int NT = K >> 5;

  // staging: thread covers 16B: row = tid>>2 (0..63), chunk = tid&3; source chunk
  // pre-XOR'd with (row>>1)&3 so linear LDS dest == swizzled layout (rule #21)
  const int srow = tid >> 2;
  const int sswz = ((tid & 3) ^ ((tid >> 3) & 3)) << 3;
  const unsigned short* AgS = A  + (size_t)(bm + srow) * K + sswz;
  const unsigned short* BgS = Bw + (size_t)(bn + srow) * K + sswz;

  // read offsets: frag row = base+lrow; (row>>1)&3 == (lrow>>1)&3 (bases are mult of 16)
  const int coff = (lhi ^ ((lrow >> 1) & 3)) << 3;
  int aoff[4], boff[4];
#pragma unroll
  for (int m = 0; m < 4; ++m) aoff[m] = (wr * 64 + m * 16 + lrow) * 32 + coff;
#pragma unroll
  for (int n = 0; n < 4; ++n) boff[n] = 4096 + (wc * 64 + n * 16 + lrow) * 32 + coff;

  f32x4 acc[4][4] = {};

  auto stage = [&](int t, unsigned short* buf) {
    const unsigned short* ag = AgS + (size_t)t * 32;
    const unsigned short* bg = BgS + (size_t)t * 32;
    gload16(ag,                  buf + tid * 8);           // A rows 0-63
    gload16(ag + (size_t)64 * K, buf + 2048 + tid * 8);    // A rows 64-127
    gload16(bg,                  buf + 4096 + tid * 8);    // B rows 0-63
    gload16(bg + (size_t)64 * K, buf + 6144 + tid * 8);    // B rows 64-127
  };

  stage(0, &Sh[0][0]);

  for (int t = 0; t < NT; ++t) {
    if (t + 1 < NT) {
      stage(t + 1, &Sh[(t + 1) & 1][0]);
      asm volatile("s_waitcnt vmcnt(4)" ::: "memory");   // stage(t) landed; t+1 in flight
    } else {
      asm volatile("s_waitcnt vmcnt(0)" ::: "memory");   // last tile: drain
    }
    __builtin_amdgcn_s_barrier();                        // all waves' stage(t) landed
    asm volatile("" ::: "memory");                       // pin ds_reads below the barrier

    const unsigned short* cb = &Sh[t & 1][0];
    bf16x8 af[4], bfr[4];
#pragma unroll
    for (int m = 0; m < 4; ++m) af[m]  = *(const bf16x8*)(cb + aoff[m]);
#pragma unroll
    for (int n = 0; n < 4; ++n) bfr[n] = *(const bf16x8*)(cb + boff[n]);
    __builtin_amdgcn_s_setprio(1);
#pragma unroll
    for (int m = 0; m < 4; ++m)
#pragma unroll
      for (int n = 0; n < 4; ++n)
        acc[m][n] = __builtin_amdgcn_mfma_f32_16x16x32_bf16(af[m], bfr[n], acc[m][n], 0, 0, 0);
    __builtin_amdgcn_s_setprio(0);
    __builtin_amdgcn_s_barrier();                        // reads(t) done before buf reuse
  }

  // ---- epilogue: C/D layout col=lane&15 (N), row=(lane>>4)*4+r (M)
#pragma unroll
  for (int m = 0; m < 4; ++m) {
    const int row0 = bm + wr * 64 + m * 16 + lhi * 4;
#pragma unroll
    for (int n = 0; n < 4; ++n) {
      const int col = bn + wc * 64 + n * 16 + lrow;
#pragma unroll
      for (int r = 0; r < 4; ++r) {
        const int row = row0 + r;
        const float v = acc[m][n][r];
        if (MODE == 0) {
          const int which = col >> 11;
          const int h = (col >> 6) & 31;
          const int d = col & 63;
          const int b = row >> 11;
          const int s = row & 2047;
          if (which == 2) {
            // V transposed: region + [b*32+h][d][s]
            Cq[(size_t)16777216 + ((size_t)(b * 32 + h) * 64 + d) * 2048 + s] = f2bf(v);
          } else {
            Cq[(((size_t)which * 64 + b * 32 + h) * 2048 + s) * 64 + d] = f2bf(v);
          }
        } else {
          Cf[(size_t)row * N + col] = v;
        }
      }
    }
  }
}

// ---------------- flash attention, fixed-shift softmax + ones-MFMA row-sum ----------------
__global__ __launch_bounds__(256)
void attn_kernel(const unsigned short* __restrict__ QKV,
                 const float* __restrict__ mask,
                 unsigned short* __restrict__ Ctx)
{
  constexpr int S = 2048, D = 64, BH = 64;
  __shared__ unsigned short Klds[2][64 * 64];
  __shared__ unsigned short Vlds[2][64 * 64];
  __shared__ unsigned short PT[4][64 * 16];

  const int tid  = threadIdx.x;
  const int lane = tid & 63;
  const int wid  = tid >> 6;
  const int lrow = lane & 15;
  const int lhi  = lane >> 4;
  const int bh = blockIdx.y;
  const int b  = bh >> 5;
  const int h  = bh & 31;
  const int qbase = blockIdx.x * 64;

  const size_t qoff = (size_t)bh * S * D;
  const size_t koff = qoff + (size_t)BH * S * D;
  const size_t voff = koff + (size_t)BH * S * D;   // V^T region: [d][s]

  bf16x8 qa0, qa1;
  {
    const unsigned short* Qp = QKV + qoff + (size_t)(qbase + wid * 16 + lrow) * D + lhi * 8;
    qa0 = *(const bf16x8*)Qp;
    qa1 = *(const bf16x8*)(Qp + 32);
  }

  bf16x8 vones;
#pragma unroll
  for (int j = 0; j < 8; ++j) vones[j] = (__bf16)1.0f;

  f32x4 oacc[4] = {};
  f32x4 osum = {};    // row-sum via ones-MFMA; same (lhi*4+r) row mapping as oacc

  const int strow  = tid >> 3;
  const int sswz   = ((tid & 7) ^ (strow & 7)) << 3;
  const unsigned short* Kg = QKV + koff + (size_t)strow * D + sswz;
  const unsigned short* Vg = QKV + voff + (size_t)strow * S + sswz;

  const float k1 = 0.125f * 1.44269504f;  // (1/sqrt(64)) * log2(e)
  const unsigned ptbase =
      (unsigned)(uintptr_t)&PT[wid][0] + (unsigned)(lane * 8 + (lane >> 4) * 128);

  auto stage = [&](int t, int c) {
    const int kb = t * 64;
    gload16(Kg + (size_t)kb * D,          &Klds[c][0] + tid * 8);
    gload16(Kg + (size_t)kb * D + 32 * D, &Klds[c][0] + 2048 + tid * 8);
    gload16(Vg + kb,                      &Vlds[c][0] + tid * 8);
    gload16(Vg + kb + 32 * S,             &Vlds[c][0] + 2048 + tid * 8);
  };

  stage(0, 0);
  __syncthreads();

  for (int t = 0; t < S / 64; ++t) {
    const int kb  = t * 64;
    const int cur = t & 1;
    if (t + 1 < S / 64) stage(t + 1, cur ^ 1);

    float mkl[4];
#pragma unroll
    for (int f = 0; f < 4; ++f)
      mkl[f] = mask[(size_t)b * S + kb + lrow + 16 * f] * 1.44269504f;

    const unsigned short* Kc = &Klds[cur][0];
    f32x4 sacc[4] = {};
    __builtin_amdgcn_s_setprio(1);
#pragma unroll
    for (int f = 0; f < 4; ++f) {
      const int krw = f * 16 + lrow;
      bf16x8 kf0 = *(const bf16x8*)(Kc + krw * 64 + ((lhi ^ (lrow & 7)) << 3));
      bf16x8 kf1 = *(const bf16x8*)(Kc + krw * 64 + (((lhi + 4) ^ (lrow & 7)) << 3));
      sacc[f] = __builtin_amdgcn_mfma_f32_16x16x32_bf16(qa0, kf0, sacc[f], 0, 0, 0);
      sacc[f] = __builtin_amdgcn_mfma_f32_16x16x32_bf16(qa1, kf1, sacc[f], 0, 0, 0);
    }
    __builtin_amdgcn_s_setprio(0);

    // fixed-shift softmax: p = exp2(s*k1 + mask); row-sum deferred to ones-MFMA
#pragma unroll
    for (int f = 0; f < 4; ++f)
#pragma unroll
      for (int r = 0; r < 4; ++r)
        sacc[f][r] = __builtin_amdgcn_exp2f(sacc[f][r] * k1 + mkl[f]);

    // P^T pack into PT[k][q] ([64][16] row-major), packed b64 writes
    unsigned short* PTw = &PT[wid][0];
#pragma unroll
    for (int f = 0; f < 4; ++f) {
      unsigned w0, w1;
      asm("v_cvt_pk_bf16_f32 %0, %1, %2" : "=v"(w0) : "v"(sacc[f][0]), "v"(sacc[f][1]));
      asm("v_cvt_pk_bf16_f32 %0, %1, %2" : "=v"(w1) : "v"(sacc[f][2]), "v"(sacc[f][3]));
      uint2v w; w.x = w0; w.y = w1;
      *(uint2v*)(PTw + (lrow + 16 * f) * 16 + lhi * 4) = w;
    }

    // PV: O += P[16x64] * V[64x64]; osum += P * ones
    const unsigned short* Vc = &Vlds[cur][0];
    uint2v r0, r1, r2, r3;
    asm volatile("ds_read_b64_tr_b16 %0, %1"             : "=v"(r0) : "v"(ptbase) : "memory");
    asm volatile("ds_read_b64_tr_b16 %0, %1 offset:128"  : "=v"(r1) : "v"(ptbase) : "memory");
    asm volatile("ds_read_b64_tr_b16 %0, %1 offset:1024" : "=v"(r2) : "v"(ptbase) : "memory");
    asm volatile("ds_read_b64_tr_b16 %0, %1 offset:1152" : "=v"(r3) : "v"(ptbase) : "memory");
    bf16x8 vb[2][4];
#pragma unroll
    for (int ks = 0; ks < 2; ++ks)
#pragma unroll
      for (int f = 0; f < 4; ++f) {
        const int dc = lrow + 16 * f;
        vb[ks][f] = *(const bf16x8*)(Vc + dc * 64 + (((ks * 4 + lhi) ^ (dc & 7)) << 3));
      }
    asm volatile("s_waitcnt lgkmcnt(0)" ::: "memory");
    __builtin_amdgcn_sched_barrier(0);
    union { struct { uint2v a, b; } u; bf16x8 v; } p0, p1;
    p0.u.a = r0; p0.u.b = r1;
    p1.u.a = r2; p1.u.b = r3;
    __builtin_amdgcn_s_setprio(1);
#pragma unroll
    for (int f = 0; f < 4; ++f)
      oacc[f] = __builtin_amdgcn_mfma_f32_16x16x32_bf16(p0.v, vb[0][f], oacc[f], 0, 0, 0);
    osum = __builtin_amdgcn_mfma_f32_16x16x32_bf16(p0.v, vones, osum, 0, 0, 0);
#pragma unroll
    for (int f = 0; f < 4; ++f)
      oacc[f] = __builtin_amdgcn_mfma_f32_16x16x32_bf16(p1.v, vb[1][f], oacc[f], 0, 0, 0);
    osum = __builtin_amdgcn_mfma_f32_16x16x32_bf16(p1.v, vones, osum, 0, 0, 0);
    __builtin_amdgcn_s_setprio(0);
    __syncthreads();
  }

  // write ctx [B,S,HID] bf16, fusing [B,H,S,D] -> [B,S,H*D]
#pragma unroll
  for (int f = 0; f < 4; ++f) {
    const int d = lrow + 16 * f;
#pragma unroll
    for (int r = 0; r < 4; ++r) {
      const int q = qbase + wid * 16 + lhi * 4 + r;
      const float v = oacc[f][r] / osum[r];
      Ctx[((size_t)b * S + q) * 2048 + h * 64 + d] = f2bf(v);
    }
  }
}

// ---------------- launch ----------------
extern "C" void kernel_launch(void* const* d_in, const int* in_sizes, int n_in,
                              void* d_out, int out_size, void* d_ws, size_t ws_size,
                              hipStream_t stream) {
  const float* X    = (const float*)d_in[0];
  const float* mask = (const float*)d_in[1];
  const float* wq   = (const float*)d_in[2];
  const float* wk   = (const float*)d_in[3];
  const float* wv   = (const float*)d_in[4];
  const float* wo   = (const float*)d_in[5];

  unsigned short* ws   = (unsigned short*)d_ws;
  unsigned short* Xb   = ws;                    //  8,388,608  X bf16 [4096][2048]
  unsigned short* Wcat = Xb + 8388608;          // 12,582,912  [Wq;Wk;Wv] bf16 [6144][2048]
  unsigned short* Wob  = Wcat + 12582912;       //  4,194,304  Wo bf16 [2048][2048]
  unsigned short* QKVb = Wob + 4194304;         // 25,165,824  Q,K: [bh][s][d]; V: [bh][d][s]
  unsigned short* Ctxb = QKVb + 25165824;       //  8,388,608  ctx bf16 [4096][2048]

  cvt_kernel<<<8192, 256, 0, stream>>>(X, Xb);
  cvt_kernel<<<4096, 256, 0, stream>>>(wq, Wcat);
  cvt_kernel<<<4096, 256, 0, stream>>>(wk, Wcat + 4194304);
  cvt_kernel<<<4096, 256, 0, stream>>>(wv, Wcat + 8388608);
  cvt_kernel<<<4096, 256, 0, stream>>>(wo, Wob);

  // QKV projection: grid 48x32 = 1536 blocks (zero tail), default dispatch order
  gemm128<0><<<dim3(48, 32), 256, 0, stream>>>(Xb, Wcat, nullptr, QKVb, 4096, 6144, 2048);

  // flash attention over 64 (b,h) pairs x 32 q-tiles
  attn_kernel<<<dim3(32, 64), 256, 0, stream>>>(QKVb, mask, Ctxb);

  // output projection: grid 16x32 = 512 blocks (zero tail)
  gemm128<1><<<dim3(16, 32), 256, 0, stream>>>(Ctxb, Wob, (float*)d_out, nullptr, 4096, 2048, 2048);
}